// Round 1
// baseline (445.999 us; speedup 1.0000x reference)
//
#include <hip/hip_runtime.h>
#include <math.h>

typedef __bf16 bf16;
typedef __attribute__((ext_vector_type(8))) __bf16 bf16x8;
typedef __attribute__((ext_vector_type(4))) __bf16 bf16x4;
typedef __attribute__((ext_vector_type(4))) float f32x4;

#define NHEADS 12
#define HDIM 64
#define BATCH 4
#define SEQ 2048
#define CDIM 768
#define MTOK (BATCH * SEQ)                    // 8192 tokens
#define PERPART ((size_t)MTOK * CDIM)         // 6291456 elems
#define NBH (BATCH * NHEADS)                  // 48
#define NKB (SEQ / 2 / 32)                    // 32 key blocks (32 keys) per half

// K pre-scale: log2(e)/8 -> softmax exp becomes a single 2^x
#define KSCALE 0.18033688011112042f
// constant shift inside exp2 (cancels exactly in normalization)
#define SHIFT 11.54156032f

// async 16B global->LDS DMA (gfx950). lds ptr wave-uniform; HW adds lane*16.
// One wave-instruction covers 64 granules = 1024 B = 512 bf16 elements.
__device__ static inline void load_lds_16(const void* g, void* l)
{
    __builtin_amdgcn_global_load_lds(
        (const __attribute__((address_space(1))) unsigned int*)g,
        (__attribute__((address_space(3))) unsigned int*)l, 16, 0, 0);
}

// ---------------------------------------------------------------------------
// convert fp32 -> bf16, 8 elems/thread
// ---------------------------------------------------------------------------
__global__ __launch_bounds__(256)
void convert_bf16(const float* __restrict__ in, bf16* __restrict__ out)
{
    const size_t i = ((size_t)blockIdx.x * 256 + threadIdx.x) * 8;
    const float4 v0 = *(const float4*)(in + i);
    const float4 v1 = *(const float4*)(in + i + 4);
    alignas(16) bf16 o[8];
    o[0] = (bf16)v0.x; o[1] = (bf16)v0.y; o[2] = (bf16)v0.z; o[3] = (bf16)v0.w;
    o[4] = (bf16)v1.x; o[5] = (bf16)v1.y; o[6] = (bf16)v1.z; o[7] = (bf16)v1.w;
    *(uint4*)(out + i) = *(const uint4*)o;
}

// ---------------------------------------------------------------------------
// transpose+convert: in fp32 [R][C] -> out bf16 [C][R]; 64x64 tiles
// ---------------------------------------------------------------------------
__global__ __launch_bounds__(256)
void transpose_convert(const float* __restrict__ in, bf16* __restrict__ out,
                       int R, int C)
{
    __shared__ bf16 T[64][65];
    const int r0 = blockIdx.y * 64, c0 = blockIdx.x * 64;
    const int t = threadIdx.x;
    const int ir = t >> 2, ic = (t & 3) * 16;
    #pragma unroll
    for (int e = 0; e < 16; ++e)
        T[ir][ic + e] = (bf16)in[(size_t)(r0 + ir) * C + c0 + ic + e];
    __syncthreads();
    const int oc = t >> 2, orr = (t & 3) * 16;
    alignas(16) bf16 tmp[16];
    #pragma unroll
    for (int e = 0; e < 16; ++e)
        tmp[e] = T[orr + e][oc];
    bf16* dst = out + (size_t)(c0 + oc) * R + r0 + orr;
    *(uint4*)dst       = *(const uint4*)tmp;
    *(uint4*)(dst + 8) = *(const uint4*)(tmp + 8);
}

// ---------------------------------------------------------------------------
// m97-style GEMM: C[M x NCOLS] = A[M x 768] @ Bt^T. 128x128 tile, BK=32,
// 4 waves (2x2). MODE 0: QKV epilogue -> q, k(*log2e/8), vT bf16 (vT stored
// with per-32-key permutation so attention PV B-fragments are contiguous).
// MODE 1: proj epilogue -> + bias, fp32 out.
// ---------------------------------------------------------------------------
template<int NCOLS, int MODE>
__global__ __launch_bounds__(256)
void gemm128(const bf16* __restrict__ A, const bf16* __restrict__ Bt,
             const float* __restrict__ bias,
             bf16* __restrict__ qb, bf16* __restrict__ kb, bf16* __restrict__ vtb,
             float* __restrict__ outf)
{
    __shared__ bf16 As[128 * 32];
    __shared__ bf16 Bs[128 * 32];

    const int t    = threadIdx.x;
    const int w    = t >> 6, lane = t & 63;
    const int ln   = lane & 15, quad = lane >> 4;
    const int wr   = w >> 1, wc = w & 1;
    const int m0   = blockIdx.x * 128, n0 = blockIdx.y * 128;

    f32x4 acc[4][4] = {};

    for (int k0 = 0; k0 < CDIM; k0 += 32) {
        #pragma unroll
        for (int i = 0; i < 2; ++i) {
            const int S   = (w * 2 + i) * 64 + lane;     // 16B slot id
            const int row = S >> 2, st = S & 3;
            const int g   = st ^ (row & 3);
            load_lds_16(A  + (size_t)(m0 + row) * CDIM + k0 + g * 8,
                        &As[(w * 2 + i) * 512]);
            load_lds_16(Bt + (size_t)(n0 + row) * CDIM + k0 + g * 8,
                        &Bs[(w * 2 + i) * 512]);
        }
        __syncthreads();

        bf16x8 af[4], bf_[4];
        #pragma unroll
        for (int mt = 0; mt < 4; ++mt) {
            const int row = wr * 64 + mt * 16 + ln;
            af[mt] = *(const bf16x8*)&As[row * 32 + (quad ^ (row & 3)) * 8];
        }
        #pragma unroll
        for (int nt = 0; nt < 4; ++nt) {
            const int row = wc * 64 + nt * 16 + ln;
            bf_[nt] = *(const bf16x8*)&Bs[row * 32 + (quad ^ (row & 3)) * 8];
        }
        #pragma unroll
        for (int mt = 0; mt < 4; ++mt)
            #pragma unroll
            for (int nt = 0; nt < 4; ++nt)
                acc[mt][nt] = __builtin_amdgcn_mfma_f32_16x16x32_bf16(
                    af[mt], bf_[nt], acc[mt][nt], 0, 0, 0);
        __syncthreads();
    }

    #pragma unroll
    for (int nt = 0; nt < 4; ++nt) {
        const int c = n0 + wc * 64 + nt * 16 + ln;
        if constexpr (MODE == 0) {
            const int p = c / CDIM, rem = c - p * CDIM;
            const int h = rem >> 6, d = rem & 63;
            #pragma unroll
            for (int mt = 0; mt < 4; ++mt) {
                const int row0 = m0 + wr * 64 + mt * 16 + quad * 4;
                const int b = row0 >> 11, nn = row0 & 2047;
                if (p == 0) {
                    bf16* dst = qb + ((size_t)(b * NHEADS + h) * SEQ + nn) * HDIM + d;
                    #pragma unroll
                    for (int r = 0; r < 4; ++r) dst[r * HDIM] = (bf16)acc[mt][nt][r];
                } else if (p == 1) {
                    bf16* dst = kb + ((size_t)(b * NHEADS + h) * SEQ + nn) * HDIM + d;
                    #pragma unroll
                    for (int r = 0; r < 4; ++r) dst[r * HDIM] = (bf16)(acc[mt][nt][r] * KSCALE);
                } else {
                    // key-permuted V^T: within each 32-key group,
                    // j = ((n>>2)&3)*8 + ((n>>4)&1)*4 + (n&3)
                    // so a lane's 8-element PV B-fragment is one 16B LDS read.
                    alignas(8) bf16 pk[4];
                    #pragma unroll
                    for (int r = 0; r < 4; ++r) pk[r] = (bf16)acc[mt][nt][r];
                    const int nn2 = (nn & ~31) + ((nn >> 2) & 3) * 8 + ((nn >> 4) & 1) * 4;
                    *(uint2*)(vtb + ((size_t)(b * NHEADS + h) * HDIM + d) * SEQ + nn2) =
                        *(const uint2*)pk;
                }
            }
        } else {
            const float bv = bias[c];
            #pragma unroll
            for (int mt = 0; mt < 4; ++mt) {
                const int row0 = m0 + wr * 64 + mt * 16 + quad * 4;
                #pragma unroll
                for (int r = 0; r < 4; ++r)
                    outf[(size_t)(row0 + r) * CDIM + c] = acc[mt][nt][r] + bv;
            }
        }
    }
}

// ---------------------------------------------------------------------------
// Flash attention v6: 32-key blocks, 16KB LDS double-buffer -> all 6
// blocks/CU co-resident (one dispatch round, was 5+1 two-round at 32KB).
// V^T is key-permuted by the QKV GEMM so the PV B-fragment is a single
// ds_read_b128 (was 2x ds_read_b64 + repack). Row sums via all-ones-B MFMA.
// Writes UNNORMALIZED bf16 O-partials + f32 rs-partials; combine merges
// the two key-halves. grid (SEQ/128, NBH, 2).
// ---------------------------------------------------------------------------
__global__ __launch_bounds__(256, 6)
void attn_kernel(const bf16* __restrict__ Qg, const bf16* __restrict__ Kg,
                 const bf16* __restrict__ Vtg,
                 bf16* __restrict__ Op, float* __restrict__ rsp)
{
    __shared__ bf16 Ks[2][32 * 64];        // [key][d], double-buffered (4KB each)
    __shared__ bf16 Vs[2][64 * 32];        // [d][key-permuted], double-buffered

    const int t    = threadIdx.x;
    const int w    = t >> 6, lane = t & 63;
    const int ln   = lane & 15, quad = lane >> 4;
    const int bh   = blockIdx.y, q0 = blockIdx.x * 128;
    const int z    = blockIdx.z;
    const int kbase = z * (SEQ / 2);       // first key of this half

    const bf16* Qb = Qg  + (size_t)bh * SEQ * HDIM;
    const bf16* Kb = Kg  + (size_t)bh * SEQ * HDIM;
    const bf16* Vb = Vtg + (size_t)bh * HDIM * SEQ;

    // Q fragments straight from global (16B aligned, one-time)
    bf16x8 qf[2][2];
    #pragma unroll
    for (int qt = 0; qt < 2; ++qt)
        #pragma unroll
        for (int kk = 0; kk < 2; ++kk) {
            const int row = w * 32 + qt * 16 + ln;
            qf[qt][kk] = *(const bf16x8*)(Qb + (size_t)(q0 + row) * HDIM
                                          + (kk * 4 + quad) * 8);
        }

    // staging geometry: 256 granules per 4KB tile, 64 per wave, 1 instr each
    const int S    = w * 64 + lane;        // granule id
    const int krow = S >> 3, kg = (S & 7) ^ (krow & 7);   // K: [32 keys][64 d]
    const int vrow = S >> 2, vg = (S & 3) ^ (vrow & 3);   // V: [64 d][32 keys]

    // stage key-block 0 of this half into buf 0
    load_lds_16(Kb + (size_t)(kbase + krow) * HDIM + kg * 8, &Ks[0][w * 512]);
    load_lds_16(Vb + (size_t)vrow * SEQ + kbase + vg * 8,    &Vs[0][w * 512]);
    __syncthreads();

    bf16x8 ones;
    #pragma unroll
    for (int e = 0; e < 8; ++e) ones[e] = (bf16)1.0f;

    f32x4 o_acc[2][4] = {};
    f32x4 racc[2] = {};                    // row sums, C-layout rows = quad*4+r

    for (int kb = 0; kb < NKB; ++kb) {
        // prefetch next key-block (drains at barrier below, overlapped)
        if (kb + 1 < NKB) {
            const int nb   = (kb + 1) & 1;
            const int kpos = kbase + (kb + 1) * 32;
            load_lds_16(Kb + (size_t)(kpos + krow) * HDIM + kg * 8, &Ks[nb][w * 512]);
            load_lds_16(Vb + (size_t)vrow * SEQ + kpos + vg * 8,    &Vs[nb][w * 512]);
        }

        const bf16* Ksb = Ks[kb & 1];
        const bf16* Vsb = Vs[kb & 1];

        union { bf16x8 v8; bf16x4 v4[2]; } pf8[2];
        #pragma unroll
        for (int sub = 0; sub < 2; ++sub) {          // two 16-key tiles
            bf16x8 ka[2];
            #pragma unroll
            for (int kk = 0; kk < 2; ++kk) {
                const int row = sub * 16 + ln;
                const int g = (kk * 4 + quad) ^ (row & 7);
                ka[kk] = *(const bf16x8*)&Ksb[row * 64 + g * 8];
            }
            #pragma unroll
            for (int qt = 0; qt < 2; ++qt) {
                f32x4 a = {-SHIFT, -SHIFT, -SHIFT, -SHIFT};
                a = __builtin_amdgcn_mfma_f32_16x16x32_bf16(ka[0], qf[qt][0], a, 0, 0, 0);
                a = __builtin_amdgcn_mfma_f32_16x16x32_bf16(ka[1], qf[qt][1], a, 0, 0, 0);
                bf16x4 pb = { (bf16)exp2f(a[0]), (bf16)exp2f(a[1]),
                              (bf16)exp2f(a[2]), (bf16)exp2f(a[3]) };
                pf8[qt].v4[sub] = pb;
            }
        }
        // row sums on the MFMA pipe: B = all-ones
        #pragma unroll
        for (int qt = 0; qt < 2; ++qt)
            racc[qt] = __builtin_amdgcn_mfma_f32_16x16x32_bf16(
                pf8[qt].v8, ones, racc[qt], 0, 0, 0);
        // O += P(32 keys) * V; permuted Vs -> single b128 per fragment
        #pragma unroll
        for (int dt = 0; dt < 4; ++dt) {
            const int row = dt * 16 + ln;               // d
            const int g = quad ^ (row & 3);
            const bf16x8 vvv = *(const bf16x8*)&Vsb[row * 32 + g * 8];
            #pragma unroll
            for (int qt = 0; qt < 2; ++qt)
                o_acc[qt][dt] = __builtin_amdgcn_mfma_f32_16x16x32_bf16(
                    pf8[qt].v8, vvv, o_acc[qt][dt], 0, 0, 0);
        }
        __syncthreads();   // drains prefetch (overlapped) + guards buffer swap
    }

    // epilogue: unnormalized partials. Op layout [z*NBH+bh][q][d]
    bf16* Ob = Op + (size_t)(z * NBH + bh) * SEQ * HDIM;
    #pragma unroll
    for (int qt = 0; qt < 2; ++qt)
        #pragma unroll
        for (int dt = 0; dt < 4; ++dt) {
            const int d = dt * 16 + ln;
            #pragma unroll
            for (int r = 0; r < 4; ++r) {
                const int q = q0 + w * 32 + qt * 16 + quad * 4 + r;
                Ob[(size_t)q * HDIM + d] = (bf16)o_acc[qt][dt][r];
            }
        }
    if (ln == 0) {
        float* rb = rsp + (size_t)(z * NBH + bh) * SEQ;
        #pragma unroll
        for (int qt = 0; qt < 2; ++qt)
            #pragma unroll
            for (int r = 0; r < 4; ++r)
                rb[q0 + w * 32 + qt * 16 + quad * 4 + r] = racc[qt][r];
    }
}

// ---------------------------------------------------------------------------
// combine: ao[b, q, h*64+d] = (O0 + O1) / (rs0 + rs1). grid (SEQ/32, NBH).
// ---------------------------------------------------------------------------
__global__ __launch_bounds__(256)
void attn_combine(const bf16* __restrict__ Op, const float* __restrict__ rsp,
                  bf16* __restrict__ ao)
{
    const int t  = threadIdx.x;
    const int bh = blockIdx.y;
    const int q  = blockIdx.x * 32 + (t >> 3);
    const int d0 = (t & 7) * 8;

    const float inv = 1.0f / (rsp[(size_t)bh * SEQ + q] +
                              rsp[(size_t)(NBH + bh) * SEQ + q]);
    const bf16x8 a = *(const bf16x8*)(Op + ((size_t)bh * SEQ + q) * HDIM + d0);
    const bf16x8 b = *(const bf16x8*)(Op + ((size_t)(NBH + bh) * SEQ + q) * HDIM + d0);

    const int bb = bh / NHEADS, h = bh % NHEADS;
    alignas(16) bf16 o[8];
    #pragma unroll
    for (int e = 0; e < 8; ++e)
        o[e] = (bf16)(((float)a[e] + (float)b[e]) * inv);
    *(uint4*)(ao + (size_t)(bb * SEQ + q) * CDIM + h * HDIM + d0) = *(const uint4*)o;
}

// ---------------------------------------------------------------------------
extern "C" void kernel_launch(void* const* d_in, const int* in_sizes, int n_in,
                              void* d_out, int out_size, void* d_ws, size_t ws_size,
                              hipStream_t stream)
{
    const float* x     = (const float*)d_in[0];
    const float* Wqkv  = (const float*)d_in[1];
    const float* Wproj = (const float*)d_in[2];
    const float* bproj = (const float*)d_in[3];
    float* out = (float*)d_out;

    bf16* ws   = (bf16*)d_ws;
    bf16* xb   = ws;                                   // [8192][768]
    bf16* wqt  = xb  + PERPART;                        // [2304][768]
    bf16* wpt  = wqt + (size_t)3 * CDIM * CDIM;        // [768][768]
    bf16* q    = wpt + (size_t)CDIM * CDIM;            // [bh][2048][64]
    bf16* k    = q   + PERPART;                        // scaled by log2e/8
    bf16* vt   = k   + PERPART;                        // [bh][64][2048] key-permuted
    bf16* ao   = vt  + PERPART;                        // [8192][768]
    bf16* op   = ao  + PERPART;                        // [2*48][2048][64] partials
    float* rsp = (float*)(op + (size_t)2 * NBH * SEQ * HDIM);  // [2*48][2048]

    convert_bf16<<<dim3(PERPART / (256 * 8)), 256, 0, stream>>>(x, xb);
    transpose_convert<<<dim3(3 * CDIM / 64, CDIM / 64), 256, 0, stream>>>(
        Wqkv, wqt, CDIM, 3 * CDIM);
    transpose_convert<<<dim3(CDIM / 64, CDIM / 64), 256, 0, stream>>>(
        Wproj, wpt, CDIM, CDIM);

    gemm128<3 * CDIM, 0><<<dim3(MTOK / 128, 3 * CDIM / 128), 256, 0, stream>>>(
        xb, wqt, nullptr, q, k, vt, nullptr);
    attn_kernel<<<dim3(SEQ / 128, NBH, 2), 256, 0, stream>>>(q, k, vt, op, rsp);
    attn_combine<<<dim3(SEQ / 32, NBH), 256, 0, stream>>>(op, rsp, ao);
    gemm128<CDIM, 1><<<dim3(MTOK / 128, CDIM / 128), 256, 0, stream>>>(
        ao, wpt, bproj, nullptr, nullptr, nullptr, out);
}